// Round 16
// baseline (139.139 us; speedup 1.0000x reference)
//
#include <hip/hip_runtime.h>

// InteractionNetwork B=4, N=256, D=128, L=3.
// agg = (sum_j adj_ij * relu(xi_i + xj_j)) @ ew2 + rowsum(adj)_i * eb2  (eb1 folded into xi)
// R14 lesson: LDS-staged weights fixed the scratch blowup (122us best), but grid=256
// (1 block/CU) leaves the 14-phase serial chain fully exposed (~19us/dispatch vs ~6 work).
// R15: 2 rows/block, 256 thr, grid 512 = 2 blocks/CU -> block B's compute hides block A's
// stage/barrier latency. LDS ~75KB (single W buffer). P2/P3 merged via reg accumulator.

#define DD 128
#define NN 256

// stage one 64KB [128][128] f32 matrix into LDS W; 256 threads x 16 float4,
// in two transient batches of 8 (peak ~32 staging VGPRs, no live range across compute).
#define STAGE(SRC) do { \
  const float4* _sp = (const float4*)(SRC); \
  float4* _wp = (float4*)W; \
  { float4 b0=_sp[t],b1=_sp[t+256],b2=_sp[t+512],b3=_sp[t+768], \
           b4=_sp[t+1024],b5=_sp[t+1280],b6=_sp[t+1536],b7=_sp[t+1792]; \
    _wp[t]=b0; _wp[t+256]=b1; _wp[t+512]=b2; _wp[t+768]=b3; \
    _wp[t+1024]=b4; _wp[t+1280]=b5; _wp[t+1536]=b6; _wp[t+1792]=b7; } \
  { float4 b0=_sp[t+2048],b1=_sp[t+2304],b2=_sp[t+2560],b3=_sp[t+2816], \
           b4=_sp[t+3072],b5=_sp[t+3328],b6=_sp[t+3584],b7=_sp[t+3840]; \
    _wp[t+2048]=b0; _wp[t+2304]=b1; _wp[t+2560]=b2; _wp[t+2816]=b3; \
    _wp[t+3072]=b4; _wp[t+3328]=b5; _wp[t+3584]=b6; _wp[t+3840]=b7; } \
} while (0)

#define RED2(r) (red[r][0][c] + red[r][1][c])

// per-thread: 2 rows x 64-wide k-half of [2][128] @ [128][128], weights in LDS
__device__ __forceinline__ void mm2(const float in[2][DD], const float* W,
                                    int k0, int c, float a[2]) {
#pragma unroll
  for (int kq = 0; kq < 16; ++kq) {
    const int k = k0 + kq * 4;
    const float4 i0 = *(const float4*)&in[0][k];
    const float4 i1 = *(const float4*)&in[1][k];
    const float* p0 = (const float*)&i0;
    const float* p1 = (const float*)&i1;
#pragma unroll
    for (int q = 0; q < 4; ++q) {
      const float wv = W[(k + q) * DD + c];
      a[0] = fmaf(p0[q], wv, a[0]);
      a[1] = fmaf(p1[q], wv, a[1]);
    }
  }
}

// ---------------- kproj: grid 512, block 256; 2 rows/block; 2 blocks/CU
__global__ __launch_bounds__(256, 2) void kproj(
    const float* __restrict__ x, const float* __restrict__ w,
    const float* __restrict__ b1, float* __restrict__ xi, float* __restrict__ xj)
{
  const int r0 = blockIdx.x * 2;
  const int t = threadIdx.x, c = t & 127, g = t >> 7, k0 = g * 64;
  __shared__ float W[DD * DD];
  __shared__ float xs[2][DD];
  __shared__ float red[2][2][DD];

  STAGE(w);
  if (t < 64) ((float4*)xs)[t] = ((const float4*)(x + (size_t)r0 * DD))[t];
  __syncthreads();

  { float a[2] = {0.f, 0.f};
    mm2(xs, W, k0, c, a);
    red[0][g][c] = a[0]; red[1][g][c] = a[1]; }
  __syncthreads();
  xi[(size_t)(r0 + g) * DD + c] = RED2(g) + b1[c];
  STAGE(w + DD * DD);
  __syncthreads();

  { float a[2] = {0.f, 0.f};
    mm2(xs, W, k0, c, a);
    red[0][g][c] = a[0]; red[1][g][c] = a[1]; }
  __syncthreads();
  xj[(size_t)(r0 + g) * DD + c] = RED2(g);
}

// ---------------- klayer: grid 512, block 256; block owns rows r0,r0+1 end-to-end.
__global__ __launch_bounds__(256, 2) void klayer(
    const float* __restrict__ xin, const float* __restrict__ adj,
    const float* __restrict__ xi, const float* __restrict__ xj,
    const float* __restrict__ ew2, const float* __restrict__ eb2,
    const float* __restrict__ nw1, const float* __restrict__ nb1,
    const float* __restrict__ nw2, const float* __restrict__ nb2,
    float* __restrict__ xout,
    const float* __restrict__ ew1n, const float* __restrict__ eb1n,
    float* __restrict__ xin_, float* __restrict__ xjn, const int has_next)
{
  const int r0 = blockIdx.x * 2;     // rows never straddle a batch
  const int b  = r0 >> 8;
  const int t = threadIdx.x, c = t & 127, g = t >> 7, k0 = g * 64;

  __shared__ float W[DD * DD];          // 64 KB, one staged matrix at a time
  __shared__ float adjs[2][NN];         // 2 KB
  __shared__ float xs[2][DD], hs[2][DD], ags[2][DD], ns[2][DD], os[2][DD];
  __shared__ float red[2][2][DD];       // [row][g][c] 4 KB
  __shared__ float rs[2];

  // ---- S0: stage ew2; adj rows; x rows; xi -> regs
  STAGE(ew2);
  if (t < 128)      ((float4*)adjs)[t]     = ((const float4*)(adj + (size_t)r0 * NN))[t];
  else if (t < 192) ((float4*)xs)[t - 128] = ((const float4*)(xin + (size_t)r0 * DD))[t - 128];
  const float xiv0 = xi[(size_t)r0 * DD + c];
  const float xiv1 = xi[(size_t)(r0 + 1) * DD + c];
  __syncthreads();

  // ---- A: rowsum (waves 0,1) + AGG (thread (c,g): j-half g, both rows)
  { const int w = t >> 6, lane = t & 63;
    if (w < 2) {
      float s = adjs[w][lane] + adjs[w][lane + 64] + adjs[w][lane + 128] + adjs[w][lane + 192];
#pragma unroll
      for (int off = 32; off; off >>= 1) s += __shfl_down(s, off);
      if (lane == 0) rs[w] = s;
    } }
  { float acc0 = 0.f, acc1 = 0.f;
    const float* xjp = xj + ((size_t)b * NN + g * 128) * DD + c;
#pragma unroll 8
    for (int jj = 0; jj < 128; ++jj) {
      const float xv = xjp[(size_t)jj * DD];
      const int j = g * 128 + jj;
      acc0 = fmaf(adjs[0][j], fmaxf(xiv0 + xv, 0.f), acc0);
      acc1 = fmaf(adjs[1][j], fmaxf(xiv1 + xv, 0.f), acc1);
    }
    red[0][g][c] = acc0; red[1][g][c] = acc1; }
  __syncthreads();

  // ---- F0: hs = reduce
  hs[g][c] = RED2(g);
  __syncthreads();

  // ---- P1: red = hs @ ew2
  { float a[2] = {0.f, 0.f};
    mm2(hs, W, k0, c, a);
    red[0][g][c] = a[0]; red[1][g][c] = a[1]; }
  __syncthreads();

  // ---- F1: ags = reduce + rs*eb2 ; stage nw1a (ew2 dead)
  ags[g][c] = RED2(g) + rs[g] * eb2[c];
  STAGE(nw1);
  __syncthreads();

  // ---- P2: a2 = xs @ nw1a (kept in regs across the nw1b swap)
  float a2[2] = {0.f, 0.f};
  mm2(xs, W, k0, c, a2);
  __syncthreads();

  // ---- F2: stage nw1b (nw1a dead)
  STAGE(nw1 + DD * DD);
  __syncthreads();

  // ---- P3: a2 += ags @ nw1b ; red = a2
  mm2(ags, W, k0, c, a2);
  red[0][g][c] = a2[0]; red[1][g][c] = a2[1];
  __syncthreads();

  // ---- F3: ns = relu(reduce + nb1) ; stage nw2
  ns[g][c] = fmaxf(RED2(g) + nb1[c], 0.f);
  STAGE(nw2);
  __syncthreads();

  // ---- P4: red = ns @ nw2
  { float a[2] = {0.f, 0.f};
    mm2(ns, W, k0, c, a);
    red[0][g][c] = a[0]; red[1][g][c] = a[1]; }
  __syncthreads();

  // ---- F4: x' = x + reduce + nb2 -> xout, os ; stage ew1n_a
  { const float xo = xs[g][c] + RED2(g) + nb2[c];
    xout[(size_t)(r0 + g) * DD + c] = xo;
    os[g][c] = xo; }
  if (!has_next) return;
  STAGE(ew1n);
  __syncthreads();

  // ---- P5: red = x' @ ew1n_a
  { float a[2] = {0.f, 0.f};
    mm2(os, W, k0, c, a);
    red[0][g][c] = a[0]; red[1][g][c] = a[1]; }
  __syncthreads();

  // ---- F5: xi_next ; stage ew1n_b
  xin_[(size_t)(r0 + g) * DD + c] = RED2(g) + eb1n[c];
  STAGE(ew1n + DD * DD);
  __syncthreads();

  // ---- P6: red = x' @ ew1n_b
  { float a[2] = {0.f, 0.f};
    mm2(os, W, k0, c, a);
    red[0][g][c] = a[0]; red[1][g][c] = a[1]; }
  __syncthreads();

  // ---- F6: xj_next
  xjn[(size_t)(r0 + g) * DD + c] = RED2(g);
}

extern "C" void kernel_launch(void* const* d_in, const int* in_sizes, int n_in,
                              void* d_out, int out_size, void* d_ws, size_t ws_size,
                              hipStream_t stream) {
  const float* x0  = (const float*)d_in[0];
  const float* adj = (const float*)d_in[1];
  const float* ew1 = (const float*)d_in[2];
  const float* eb1 = (const float*)d_in[3];
  const float* ew2 = (const float*)d_in[4];
  const float* eb2 = (const float*)d_in[5];
  const float* nw1 = (const float*)d_in[6];
  const float* nb1 = (const float*)d_in[7];
  const float* nw2 = (const float*)d_in[8];
  const float* nb2 = (const float*)d_in[9];
  float* out = (float*)d_out;
  float* ws  = (float*)d_ws;

  float* xi0 = ws;                // 131072 floats each
  float* xj0 = ws + 131072;
  float* xi1 = ws + 262144;
  float* xj1 = ws + 393216;
  float* xA  = ws + 524288;
  float* xB  = ws + 655360;

  kproj<<<512, 256, 0, stream>>>(x0, ew1, eb1, xi0, xj0);

  const float* xins[3]  = {x0, xA, xB};
  float*       xouts[3] = {xA, xB, out};
  float*       xis[2] = {xi0, xi1};
  float*       xjs[2] = {xj0, xj1};
  for (int l = 0; l < 3; ++l) {
    const int cur = l & 1, nxt = cur ^ 1;
    const int ln = (l + 1 < 3) ? (l + 1) : 0;  // dummy for last layer (unused)
    klayer<<<512, 256, 0, stream>>>(
        xins[l], adj, xis[cur], xjs[cur],
        ew2 + l * DD * DD, eb2 + l * DD,
        nw1 + l * 2 * DD * DD, nb1 + l * DD,
        nw2 + l * DD * DD, nb2 + l * DD,
        xouts[l],
        ew1 + ln * 2 * DD * DD, eb1 + ln * DD,
        xis[nxt], xjs[nxt], (l + 1 < 3) ? 1 : 0);
  }
}

// Round 17
// 120.222 us; speedup vs baseline: 1.1573x; 1.1573x over previous
//
#include <hip/hip_runtime.h>

// InteractionNetwork B=4, N=256, D=128, L=3.
// agg = (sum_j adj_ij * relu(xi_i + xj_j)) @ ew2 + rowsum(adj)_i * eb2  (eb1 folded into xi)
// R15 lesson: 2 blocks/CU doubled per-CU weight staging -> regression (139us). Back to
// R14 shape (grid 256, 512thr, 1 block/CU, 122us best).
// R16: async weight prefetch via global_load_lds (zero-VGPR DMA) into double-buffered
// W0/W1 -- each matmul phase issues next matrix's load, computes from the other buffer;
// barrier vmcnt-drain lands under compute. F1 merged into P2 (12 barriers).

#define DD 128
#define NN 256

typedef const __attribute__((address_space(1))) void* gas_ptr;
typedef __attribute__((address_space(3))) void* las_ptr;

// async-stage one 64KB [128][128] f32 matrix into LDS: 8 waves x 8 x 1KB chunks.
// LDS dest is wave-uniform base (+ lane*16 added by HW); global src is per-lane.
__device__ __forceinline__ void async_stage(const float* __restrict__ src,
                                            float* dst, int t) {
  const int wave = t >> 6, lane = t & 63;
  const float* g = src + wave * 2048 + lane * 4;
  float* l = dst + wave * 2048;
#pragma unroll
  for (int i = 0; i < 8; ++i) {
    __builtin_amdgcn_global_load_lds((gas_ptr)(g + i * 256),
                                     (las_ptr)(l + i * 256), 16, 0, 0);
  }
}

#define RED4 (red[g][0][c] + red[g][1][c] + red[g][2][c] + red[g][3][c])

// one k-quarter (32-wide) of [4 rows x 128] @ [128 x 128], weights in LDS
__device__ __forceinline__ void mm4(const float in[4][DD], const float* W,
                                    int k0, int c, float a[4]) {
#pragma unroll
  for (int kq = 0; kq < 8; ++kq) {
    const int k = k0 + kq * 4;
    const float4 i0 = *(const float4*)&in[0][k];
    const float4 i1 = *(const float4*)&in[1][k];
    const float4 i2 = *(const float4*)&in[2][k];
    const float4 i3 = *(const float4*)&in[3][k];
    const float* p0 = (const float*)&i0;
    const float* p1 = (const float*)&i1;
    const float* p2 = (const float*)&i2;
    const float* p3 = (const float*)&i3;
#pragma unroll
    for (int q = 0; q < 4; ++q) {
      const float wv = W[(k + q) * DD + c];
      a[0] = fmaf(p0[q], wv, a[0]);
      a[1] = fmaf(p1[q], wv, a[1]);
      a[2] = fmaf(p2[q], wv, a[2]);
      a[3] = fmaf(p3[q], wv, a[3]);
    }
  }
}

// ---------------- kproj: grid 256, block 512; 4 rows/block; async dbuf weights
__global__ __launch_bounds__(512) void kproj(
    const float* __restrict__ x, const float* __restrict__ w,
    const float* __restrict__ b1, float* __restrict__ xi, float* __restrict__ xj)
{
  const int r0 = blockIdx.x * 4;
  const int t = threadIdx.x, c = t & 127, g = t >> 7, k0 = g * 32;
  __shared__ float W0[DD * DD], W1[DD * DD];
  __shared__ float xs[4][DD];
  __shared__ float red[4][4][DD];

  async_stage(w, W0, t);
  if (t < 128) ((float4*)xs)[t] = ((const float4*)(x + (size_t)r0 * DD))[t];
  __syncthreads();

  async_stage(w + DD * DD, W1, t);
  { float a[4] = {0.f,0.f,0.f,0.f};
    mm4(xs, W0, k0, c, a);
#pragma unroll
    for (int r = 0; r < 4; ++r) red[r][g][c] = a[r]; }
  __syncthreads();

  xi[(size_t)(r0 + g) * DD + c] = RED4 + b1[c];
  __syncthreads();   // red WAR by P2

  { float a[4] = {0.f,0.f,0.f,0.f};
    mm4(xs, W1, k0, c, a);
#pragma unroll
    for (int r = 0; r < 4; ++r) red[r][g][c] = a[r]; }
  __syncthreads();
  xj[(size_t)(r0 + g) * DD + c] = RED4;
}

// ---------------- klayer: grid 256, block 512; block owns 4 rows end-to-end.
__global__ __launch_bounds__(512) void klayer(
    const float* __restrict__ xin, const float* __restrict__ adj,
    const float* __restrict__ xi, const float* __restrict__ xj,
    const float* __restrict__ ew2, const float* __restrict__ eb2,
    const float* __restrict__ nw1, const float* __restrict__ nb1,
    const float* __restrict__ nw2, const float* __restrict__ nb2,
    float* __restrict__ xout,
    const float* __restrict__ ew1n, const float* __restrict__ eb1n,
    float* __restrict__ xin_, float* __restrict__ xjn, const int has_next)
{
  const int r0 = blockIdx.x * 4;     // rows never straddle a batch
  const int b  = r0 >> 8;
  const int t = threadIdx.x, c = t & 127, g = t >> 7, k0 = g * 32;

  __shared__ float W0[DD * DD], W1[DD * DD];   // 128 KB dbuf weights
  __shared__ float adjs[4][NN];
  __shared__ float xs[4][DD], hs[4][DD], ags[4][DD], ns[4][DD], os[4][DD];
  __shared__ float red[4][4][DD];
  __shared__ float rs[4];

  // ---- S0: prefetch ew2->W0 ; sync-stage adj + x ; xi -> regs
  async_stage(ew2, W0, t);
  if (t < 256)      ((float4*)adjs)[t]     = ((const float4*)(adj + (size_t)r0 * NN))[t];
  else if (t < 384) ((float4*)xs)[t - 256] = ((const float4*)(xin + (size_t)r0 * DD))[t - 256];
  float xiv[4];
#pragma unroll
  for (int r = 0; r < 4; ++r) xiv[r] = xi[(size_t)(r0 + r) * DD + c];
  __syncthreads();

  // ---- AGG: prefetch nw1a->W1 ; rowsum ; g-th j-quarter partials
  async_stage(nw1, W1, t);
  { const int w = t >> 6, lane = t & 63;
    if (w < 4) {
      float s = adjs[w][lane] + adjs[w][lane + 64] + adjs[w][lane + 128] + adjs[w][lane + 192];
#pragma unroll
      for (int off = 32; off; off >>= 1) s += __shfl_down(s, off);
      if (lane == 0) rs[w] = s;
    } }
  { float acc[4] = {0.f,0.f,0.f,0.f};
    const float* xjp = xj + ((size_t)b * NN + g * 64) * DD + c;
#pragma unroll 8
    for (int jj = 0; jj < 64; ++jj) {
      const float xv = xjp[(size_t)jj * DD];
#pragma unroll
      for (int r = 0; r < 4; ++r)
        acc[r] = fmaf(adjs[r][g * 64 + jj], fmaxf(xiv[r] + xv, 0.f), acc[r]);
    }
#pragma unroll
    for (int r = 0; r < 4; ++r) red[r][g][c] = acc[r]; }
  __syncthreads();

  // ---- F0: hs = reduce
  hs[g][c] = RED4;
  __syncthreads();

  // ---- P1: red = hs @ ew2 (W0)
  { float a[4] = {0.f,0.f,0.f,0.f};
    mm4(hs, W0, k0, c, a);
#pragma unroll
    for (int r = 0; r < 4; ++r) red[r][g][c] = a[r]; }
  __syncthreads();

  // ---- F1+P2: ags = reduce + rs*eb2 ; prefetch nw1b->W0 ; a2 = xs @ nw1a (W1)
  ags[g][c] = RED4 + rs[g] * eb2[c];
  async_stage(nw1 + DD * DD, W0, t);
  float a2[4] = {0.f,0.f,0.f,0.f};
  mm4(xs, W1, k0, c, a2);
  __syncthreads();

  // ---- P3: prefetch nw2->W1 ; a2 += ags @ nw1b (W0) ; red = a2
  async_stage(nw2, W1, t);
  mm4(ags, W0, k0, c, a2);
#pragma unroll
  for (int r = 0; r < 4; ++r) red[r][g][c] = a2[r];
  __syncthreads();

  // ---- F3: ns = relu(reduce + nb1)
  ns[g][c] = fmaxf(RED4 + nb1[c], 0.f);
  __syncthreads();

  // ---- P4: prefetch ew1na->W0 (if needed) ; red = ns @ nw2 (W1)
  if (has_next) async_stage(ew1n, W0, t);
  { float a[4] = {0.f,0.f,0.f,0.f};
    mm4(ns, W1, k0, c, a);
#pragma unroll
    for (int r = 0; r < 4; ++r) red[r][g][c] = a[r]; }
  __syncthreads();

  // ---- F4: x' = x + reduce + nb2 -> xout, os
  { const float xo = xs[g][c] + RED4 + nb2[c];
    xout[(size_t)(r0 + g) * DD + c] = xo;
    os[g][c] = xo; }
  if (!has_next) return;
  __syncthreads();

  // ---- P5: prefetch ew1nb->W1 ; red = x' @ ew1na (W0)
  async_stage(ew1n + DD * DD, W1, t);
  { float a[4] = {0.f,0.f,0.f,0.f};
    mm4(os, W0, k0, c, a);
#pragma unroll
    for (int r = 0; r < 4; ++r) red[r][g][c] = a[r]; }
  __syncthreads();

  // ---- F5: xi_next
  xin_[(size_t)(r0 + g) * DD + c] = RED4 + eb1n[c];
  __syncthreads();   // red WAR by P6

  // ---- P6: red = x' @ ew1nb (W1)
  { float a[4] = {0.f,0.f,0.f,0.f};
    mm4(os, W1, k0, c, a);
#pragma unroll
    for (int r = 0; r < 4; ++r) red[r][g][c] = a[r]; }
  __syncthreads();

  // ---- F6: xj_next
  xjn[(size_t)(r0 + g) * DD + c] = RED4;
}

extern "C" void kernel_launch(void* const* d_in, const int* in_sizes, int n_in,
                              void* d_out, int out_size, void* d_ws, size_t ws_size,
                              hipStream_t stream) {
  const float* x0  = (const float*)d_in[0];
  const float* adj = (const float*)d_in[1];
  const float* ew1 = (const float*)d_in[2];
  const float* eb1 = (const float*)d_in[3];
  const float* ew2 = (const float*)d_in[4];
  const float* eb2 = (const float*)d_in[5];
  const float* nw1 = (const float*)d_in[6];
  const float* nb1 = (const float*)d_in[7];
  const float* nw2 = (const float*)d_in[8];
  const float* nb2 = (const float*)d_in[9];
  float* out = (float*)d_out;
  float* ws  = (float*)d_ws;

  float* xi0 = ws;                // 131072 floats each
  float* xj0 = ws + 131072;
  float* xi1 = ws + 262144;
  float* xj1 = ws + 393216;
  float* xA  = ws + 524288;
  float* xB  = ws + 655360;

  kproj<<<256, 512, 0, stream>>>(x0, ew1, eb1, xi0, xj0);

  const float* xins[3]  = {x0, xA, xB};
  float*       xouts[3] = {xA, xB, out};
  float*       xis[2] = {xi0, xi1};
  float*       xjs[2] = {xj0, xj1};
  for (int l = 0; l < 3; ++l) {
    const int cur = l & 1, nxt = cur ^ 1;
    const int ln = (l + 1 < 3) ? (l + 1) : 0;  // dummy for last layer (unused)
    klayer<<<256, 512, 0, stream>>>(
        xins[l], adj, xis[cur], xjs[cur],
        ew2 + l * DD * DD, eb2 + l * DD,
        nw1 + l * 2 * DD * DD, nb1 + l * DD,
        nw2 + l * DD * DD, nb2 + l * DD,
        xouts[l],
        ew1 + ln * 2 * DD * DD, eb1 + ln * DD,
        xis[nxt], xjs[nxt], (l + 1 < 3) ? 1 : 0);
  }
}